// Round 1
// baseline (3196.516 us; speedup 1.0000x reference)
//
#include <hip/hip_runtime.h>
#include <hip/hip_bf16.h>

// GRU: BATCH=256, SEQ=512, INPUT=128, HIDDEN=256, fp32 in/out.
// Phase 1 (gru_xpre): Gx[g,t,b,j] = X[b,t,:] @ W_g[:,256:384].T + b_g  (bf16, swizzled)
// Phase 2 (gru_seq):  persistent batch-split recurrence, recurrent weights in VGPRs.
// Fallback (gru_fallback): naive fp32, used only if ws_size < 201 MB.

typedef float f32x4 __attribute__((ext_vector_type(4)));
typedef short s16x8 __attribute__((ext_vector_type(8)));

#define SEQ 512
#define NB  256
#define NI  128
#define NH  256
#define WROW 384               // W leading dim (H+I)
#define GX_BYTES ((size_t)201326592)   // 512 t * 768 chunks * 512 B

static __device__ inline unsigned f2bf(float f) {
    unsigned u = __builtin_bit_cast(unsigned, f);
    return (u + 0x7fffu + ((u >> 16) & 1u)) >> 16;   // RTNE
}
static __device__ inline float bf2f(unsigned short s) {
    unsigned u = ((unsigned)s) << 16;
    return __builtin_bit_cast(float, u);
}
static __device__ inline float fexp2(float x) {
#if __has_builtin(__builtin_amdgcn_exp2f)
    return __builtin_amdgcn_exp2f(x);
#else
    return exp2f(x);
#endif
}
static __device__ inline float frcp(float x) {
#if __has_builtin(__builtin_amdgcn_rcpf)
    return __builtin_amdgcn_rcpf(x);
#else
    return 1.0f / x;
#endif
}
static __device__ inline float sigm(float x)  { return frcp(1.0f + fexp2(-1.44269504f * x)); }
static __device__ inline float tanh_(float x) { return 1.0f - 2.0f * frcp(1.0f + fexp2(2.88539008f * x)); }

// ---------------------------------------------------------------------------
// Phase 1: input projections. One WG per timestep t. 256 thr = 4 waves.
// Output layout: chunk = (((t*16 + mt)*4 + v)*3 + g)*4 + tt, 512 B/chunk,
// lane l stores its 4 C-frag regs (m = quad*4+r) packed bf16 at chunk*512 + l*8.
// ---------------------------------------------------------------------------
__global__ __launch_bounds__(256, 1) void gru_xpre(
    const float* __restrict__ X,
    const float* __restrict__ Wz, const float* __restrict__ bz,
    const float* __restrict__ Wr, const float* __restrict__ br,
    const float* __restrict__ Wc, const float* __restrict__ bc,
    unsigned short* __restrict__ Gx)
{
    __shared__ unsigned short x_lds[32768];   // 256 rows x 128 bf16, XOR-swizzled 16B chunks
    const int tid  = threadIdx.x;
    const int t    = blockIdx.x;
    const int l    = tid & 63;
    const int v    = tid >> 6;
    const int quad = l >> 4;
    const int n    = l & 15;

    // stage X[:, t, :] -> LDS bf16 (coalesced 32B per thread)
    for (int i = tid; i < 4096; i += 256) {
        int row = i >> 4, c = i & 15;
        const float* src = X + (size_t)(row * SEQ + t) * NI + c * 8;
        f32x4 f0 = *(const f32x4*)(src);
        f32x4 f1 = *(const f32x4*)(src + 4);
        s16x8 w;
#pragma unroll
        for (int e = 0; e < 4; ++e) { w[e] = (short)f2bf(f0[e]); w[e + 4] = (short)f2bf(f1[e]); }
        *(s16x8*)(&x_lds[row * 128 + ((c ^ (row & 15)) << 3)]) = w;
    }

    // B-frags (X-part of weights, k in [256,384)) in registers: [g][tt][kt]
    const float* Wp[3] = {Wz, Wr, Wc};
    const float* bp[3] = {bz, br, bc};
    s16x8 Bf[3][4][4];
    float bias[3][4];
#pragma unroll
    for (int g = 0; g < 3; ++g) {
#pragma unroll
        for (int tt = 0; tt < 4; ++tt) {
            int j = v * 64 + tt * 16 + n;
            bias[g][tt] = bp[g][j];
#pragma unroll
            for (int kt = 0; kt < 4; ++kt) {
                const float* src = Wp[g] + j * WROW + 256 + kt * 32 + quad * 8;
                f32x4 f0 = *(const f32x4*)(src);
                f32x4 f1 = *(const f32x4*)(src + 4);
                s16x8 w;
#pragma unroll
                for (int e = 0; e < 4; ++e) { w[e] = (short)f2bf(f0[e]); w[e + 4] = (short)f2bf(f1[e]); }
                Bf[g][tt][kt] = w;
            }
        }
    }
    __syncthreads();

    const int rowA = l & 15;
#pragma unroll 1
    for (int mt = 0; mt < 16; ++mt) {
        f32x4 acc[3][4];
        f32x4 z4 = {0.f, 0.f, 0.f, 0.f};
#pragma unroll
        for (int g = 0; g < 3; ++g)
#pragma unroll
            for (int tt = 0; tt < 4; ++tt) acc[g][tt] = z4;

#pragma unroll
        for (int kt = 0; kt < 4; ++kt) {
            int row = mt * 16 + rowA;
            s16x8 a = *(const s16x8*)(&x_lds[row * 128 + (((kt * 4 + quad) ^ rowA) << 3)]);
#pragma unroll
            for (int g = 0; g < 3; ++g)
#pragma unroll
                for (int tt = 0; tt < 4; ++tt)
                    acc[g][tt] = __builtin_amdgcn_mfma_f32_16x16x32_bf16(a, Bf[g][tt][kt], acc[g][tt], 0, 0, 0);
        }

#pragma unroll
        for (int g = 0; g < 3; ++g)
#pragma unroll
            for (int tt = 0; tt < 4; ++tt) {
                unsigned r0 = f2bf(acc[g][tt][0] + bias[g][tt]);
                unsigned r1 = f2bf(acc[g][tt][1] + bias[g][tt]);
                unsigned r2 = f2bf(acc[g][tt][2] + bias[g][tt]);
                unsigned r3 = f2bf(acc[g][tt][3] + bias[g][tt]);
                uint2 d; d.x = r0 | (r1 << 16); d.y = r2 | (r3 << 16);
                int chunk = (((t * 16 + mt) * 4 + v) * 3 + g) * 4 + tt;
                *(uint2*)((char*)Gx + (size_t)chunk * 512 + l * 8) = d;
            }
    }
}

// ---------------------------------------------------------------------------
// Phase 2: persistent recurrence. 16 WGs x 256 thr (4 waves, 1 wave/SIMD).
// Recurrent weights (k<256) resident in 384 VGPRs/wave as B-frags.
// ---------------------------------------------------------------------------
__global__ __launch_bounds__(256, 1) void gru_seq(
    const float* __restrict__ Wz, const float* __restrict__ Wr, const float* __restrict__ Wc,
    const unsigned short* __restrict__ Gx,
    float* __restrict__ out)
{
    __shared__ unsigned short h_lds[16][264];    // +8 pad: 2-way-max bank aliasing on b128 reads
    __shared__ unsigned short rh_lds[16][264];

    const int tid  = threadIdx.x;
    const int wg   = blockIdx.x;
    const int l    = tid & 63;
    const int v    = tid >> 6;
    const int quad = l >> 4;
    const int n    = l & 15;
    const int rowA = l & 15;

    // preload recurrent weight fragments: Wf[g][tt][kt], j = v*64+tt*16+n, k = kt*32+quad*8
    const float* Wp[3] = {Wz, Wr, Wc};
    s16x8 Wf[3][4][8];
#pragma unroll
    for (int g = 0; g < 3; ++g)
#pragma unroll
        for (int tt = 0; tt < 4; ++tt)
#pragma unroll
            for (int kt = 0; kt < 8; ++kt) {
                int j = v * 64 + tt * 16 + n;
                const float* src = Wp[g] + j * WROW + kt * 32 + quad * 8;
                f32x4 f0 = *(const f32x4*)(src);
                f32x4 f1 = *(const f32x4*)(src + 4);
                s16x8 w;
#pragma unroll
                for (int e = 0; e < 4; ++e) { w[e] = (short)f2bf(f0[e]); w[e + 4] = (short)f2bf(f1[e]); }
                Wf[g][tt][kt] = w;
            }

    // zero h state
    {
        unsigned short* hz = &h_lds[0][0];
        for (int i = tid; i < 16 * 264; i += 256) hz[i] = 0;
    }
    float hreg[4][4];
#pragma unroll
    for (int tt = 0; tt < 4; ++tt)
#pragma unroll
        for (int r = 0; r < 4; ++r) hreg[tt][r] = 0.0f;
    __syncthreads();

    const char* gxt = (const char*)Gx + (size_t)((wg * 4 + v) * 12) * 512 + l * 8;
    float* outp = out + (wg * 16 + quad * 4) * 256 + v * 64 + n;
    const f32x4 z4 = {0.f, 0.f, 0.f, 0.f};

#pragma unroll 1
    for (int t = 0; t < SEQ; ++t) {
        const char* gb = gxt + (size_t)t * 393216;

        // issue Gx loads for z,r early (consumed ~64 MFMAs later)
        uint2 gz[4], gr[4];
#pragma unroll
        for (int tt = 0; tt < 4; ++tt) {
            gz[tt] = *(const uint2*)(gb + (0 * 4 + tt) * 512);
            gr[tt] = *(const uint2*)(gb + (1 * 4 + tt) * 512);
        }

        f32x4 accZ[4], accR[4];
#pragma unroll
        for (int tt = 0; tt < 4; ++tt) { accZ[tt] = z4; accR[tt] = z4; }

#pragma unroll
        for (int kt = 0; kt < 8; ++kt) {
            s16x8 a = *(const s16x8*)(&h_lds[rowA][kt * 32 + quad * 8]);
#pragma unroll
            for (int tt = 0; tt < 4; ++tt) {
                accZ[tt] = __builtin_amdgcn_mfma_f32_16x16x32_bf16(a, Wf[0][tt][kt], accZ[tt], 0, 0, 0);
                accR[tt] = __builtin_amdgcn_mfma_f32_16x16x32_bf16(a, Wf[1][tt][kt], accR[tt], 0, 0, 0);
            }
        }

        // epilogue 1: z, r, write r*h
        float zs[4][4];
#pragma unroll
        for (int tt = 0; tt < 4; ++tt) {
            float gzf[4] = { bf2f((unsigned short)(gz[tt].x & 0xffffu)), bf2f((unsigned short)(gz[tt].x >> 16)),
                             bf2f((unsigned short)(gz[tt].y & 0xffffu)), bf2f((unsigned short)(gz[tt].y >> 16)) };
            float grf[4] = { bf2f((unsigned short)(gr[tt].x & 0xffffu)), bf2f((unsigned short)(gr[tt].x >> 16)),
                             bf2f((unsigned short)(gr[tt].y & 0xffffu)), bf2f((unsigned short)(gr[tt].y >> 16)) };
#pragma unroll
            for (int r = 0; r < 4; ++r) {
                float zv = sigm(accZ[tt][r] + gzf[r]);
                float rv = sigm(accR[tt][r] + grf[r]);
                zs[tt][r] = zv;
                float rh = rv * hreg[tt][r];
                rh_lds[quad * 4 + r][v * 64 + tt * 16 + n] = (unsigned short)f2bf(rh);
            }
        }
        __syncthreads();   // all r*h written, all h_lds reads done

        uint2 gc[4];
#pragma unroll
        for (int tt = 0; tt < 4; ++tt) gc[tt] = *(const uint2*)(gb + (2 * 4 + tt) * 512);

        f32x4 accC[4];
#pragma unroll
        for (int tt = 0; tt < 4; ++tt) accC[tt] = z4;
#pragma unroll
        for (int kt = 0; kt < 8; ++kt) {
            s16x8 a = *(const s16x8*)(&rh_lds[rowA][kt * 32 + quad * 8]);
#pragma unroll
            for (int tt = 0; tt < 4; ++tt)
                accC[tt] = __builtin_amdgcn_mfma_f32_16x16x32_bf16(a, Wf[2][tt][kt], accC[tt], 0, 0, 0);
        }

        // epilogue 2: candidate, h update, stores
#pragma unroll
        for (int tt = 0; tt < 4; ++tt) {
            float gcf[4] = { bf2f((unsigned short)(gc[tt].x & 0xffffu)), bf2f((unsigned short)(gc[tt].x >> 16)),
                             bf2f((unsigned short)(gc[tt].y & 0xffffu)), bf2f((unsigned short)(gc[tt].y >> 16)) };
#pragma unroll
            for (int r = 0; r < 4; ++r) {
                float cv = tanh_(accC[tt][r] + gcf[r]);
                float h  = hreg[tt][r];
                float hn = fmaf(zs[tt][r], cv - h, h);
                hreg[tt][r] = hn;
                h_lds[quad * 4 + r][v * 64 + tt * 16 + n] = (unsigned short)f2bf(hn);
                outp[t * 65536 + r * 256 + tt * 16] = hn;
            }
        }
        __syncthreads();   // h_lds consistent before next step
    }
}

// ---------------------------------------------------------------------------
// Fallback (only if ws_size < 201 MB): naive fp32, correct but slow.
// ---------------------------------------------------------------------------
__global__ __launch_bounds__(1024, 1) void gru_fallback(
    const float* __restrict__ X,
    const float* __restrict__ Wz, const float* __restrict__ bz,
    const float* __restrict__ Wr, const float* __restrict__ br,
    const float* __restrict__ Wc, const float* __restrict__ bc,
    float* __restrict__ out)
{
    __shared__ float h_s[16][257];
    __shared__ float rh_s[16][257];
    __shared__ float x_s[16][128];
    const int tid = threadIdx.x;
    const int wg = blockIdx.x, b0 = wg * 16;
    const int m = tid >> 6, jq = tid & 63;
    for (int i = tid; i < 16 * 257; i += 1024) (&h_s[0][0])[i] = 0.0f;
    __syncthreads();
    for (int t = 0; t < SEQ; ++t) {
        for (int i = tid; i < 2048; i += 1024) {
            int row = i >> 7, k = i & 127;
            x_s[row][k] = X[(size_t)((b0 + row) * SEQ + t) * NI + k];
        }
        __syncthreads();
        float zv[4];
        for (int jj = 0; jj < 4; ++jj) {
            int j = jj * 64 + jq;
            float az = bz[j], ar = br[j];
            for (int k = 0; k < 256; ++k) { float h = h_s[m][k]; az += h * Wz[j * WROW + k]; ar += h * Wr[j * WROW + k]; }
            for (int k = 0; k < 128; ++k) { float x = x_s[m][k]; az += x * Wz[j * WROW + 256 + k]; ar += x * Wr[j * WROW + 256 + k]; }
            float z = sigm(az), r = sigm(ar);
            zv[jj] = z;
            rh_s[m][j] = r * h_s[m][j];
        }
        __syncthreads();
        float hn[4];
        for (int jj = 0; jj < 4; ++jj) {
            int j = jj * 64 + jq;
            float ac = bc[j];
            for (int k = 0; k < 256; ++k) ac += rh_s[m][k] * Wc[j * WROW + k];
            for (int k = 0; k < 128; ++k) ac += x_s[m][k] * Wc[j * WROW + 256 + k];
            float c = tanh_(ac);
            float h = h_s[m][j];
            hn[jj] = fmaf(zv[jj], c - h, h);
        }
        __syncthreads();
        for (int jj = 0; jj < 4; ++jj) {
            int j = jj * 64 + jq;
            h_s[m][j] = hn[jj];
            out[(size_t)(t * 256 + b0 + m) * 256 + j] = hn[jj];
        }
        __syncthreads();
    }
}

extern "C" void kernel_launch(void* const* d_in, const int* in_sizes, int n_in,
                              void* d_out, int out_size, void* d_ws, size_t ws_size,
                              hipStream_t stream) {
    const float* X  = (const float*)d_in[0];
    const float* Wz = (const float*)d_in[1];
    const float* bz = (const float*)d_in[2];
    const float* Wr = (const float*)d_in[3];
    const float* br = (const float*)d_in[4];
    const float* Wc = (const float*)d_in[5];
    const float* bc = (const float*)d_in[6];
    float* out = (float*)d_out;

    if (ws_size >= GX_BYTES) {
        unsigned short* Gx = (unsigned short*)d_ws;
        gru_xpre<<<512, 256, 0, stream>>>(X, Wz, bz, Wr, br, Wc, bc, Gx);
        gru_seq<<<16, 256, 0, stream>>>(Wz, Wr, Wc, Gx, out);
    } else {
        gru_fallback<<<16, 1024, 0, stream>>>(X, Wz, bz, Wr, br, Wc, bc, out);
    }
}

// Round 3
// 1413.841 us; speedup vs baseline: 2.2609x; 2.2609x over previous
//
#include <hip/hip_runtime.h>
#include <hip/hip_bf16.h>

// GRU: BATCH=256, SEQ=512, INPUT=128, HIDDEN=256, fp32 in/out.
// Phase 1 (gru_xpre): Gx[g,t,b,j] = X[b,t,:] @ W_g[:,256:384].T + b_g  (bf16, swizzled)
// Phase 2 (gru_seq):  persistent batch-split recurrence, 16 WGs x 512 thr (8 waves,
//   2 waves/SIMD). Wz/Wr recurrent frags in VGPRs (128), Wc frags in LDS (128 KB).
//   Barriers are lgkmcnt-only (inline asm) so Gx loads / out stores float across them.
// Fallback (gru_fallback): naive fp32, used only if ws_size < 201 MB.

typedef float f32x4 __attribute__((ext_vector_type(4)));
typedef short s16x8 __attribute__((ext_vector_type(8)));

#define SEQ 512
#define NB  256
#define NI  128
#define NH  256
#define WROW 384               // W leading dim (H+I)
#define GX_BYTES ((size_t)201326592)   // 512 t * 768 chunks * 512 B

static __device__ inline unsigned f2bf(float f) {
    unsigned u = __builtin_bit_cast(unsigned, f);
    return (u + 0x7fffu + ((u >> 16) & 1u)) >> 16;   // RTNE
}
static __device__ inline float bf2f(unsigned short s) {
    unsigned u = ((unsigned)s) << 16;
    return __builtin_bit_cast(float, u);
}
static __device__ inline float fexp2(float x) {
#if __has_builtin(__builtin_amdgcn_exp2f)
    return __builtin_amdgcn_exp2f(x);
#else
    return exp2f(x);
#endif
}
static __device__ inline float frcp(float x) {
#if __has_builtin(__builtin_amdgcn_rcpf)
    return __builtin_amdgcn_rcpf(x);
#else
    return 1.0f / x;
#endif
}
static __device__ inline float sigm(float x)  { return frcp(1.0f + fexp2(-1.44269504f * x)); }
static __device__ inline float tanh_(float x) { return 1.0f - 2.0f * frcp(1.0f + fexp2(2.88539008f * x)); }

// lgkm-only barrier: LDS visibility without draining vmem (loads/stores stay in flight)
static __device__ inline void lds_barrier() {
    asm volatile("s_waitcnt lgkmcnt(0)\n\ts_barrier" ::: "memory");
}

// ---------------------------------------------------------------------------
// Phase 1: input projections. One WG per timestep t. 256 thr = 4 waves.
// Output layout: chunk = (((t*16 + mt)*4 + v)*3 + g)*4 + tt, 512 B/chunk,
// lane l stores its 4 C-frag regs (m = quad*4+r) packed bf16 at chunk*512 + l*8.
// ---------------------------------------------------------------------------
__global__ __launch_bounds__(256, 1) void gru_xpre(
    const float* __restrict__ X,
    const float* __restrict__ Wz, const float* __restrict__ bz,
    const float* __restrict__ Wr, const float* __restrict__ br,
    const float* __restrict__ Wc, const float* __restrict__ bc,
    unsigned short* __restrict__ Gx)
{
    __shared__ unsigned short x_lds[32768];   // 256 rows x 128 bf16, XOR-swizzled 16B chunks
    const int tid  = threadIdx.x;
    const int t    = blockIdx.x;
    const int l    = tid & 63;
    const int v    = tid >> 6;
    const int quad = l >> 4;
    const int n    = l & 15;

    // stage X[:, t, :] -> LDS bf16 (coalesced 32B per thread)
    for (int i = tid; i < 4096; i += 256) {
        int row = i >> 4, c = i & 15;
        const float* src = X + (size_t)(row * SEQ + t) * NI + c * 8;
        f32x4 f0 = *(const f32x4*)(src);
        f32x4 f1 = *(const f32x4*)(src + 4);
        s16x8 w;
#pragma unroll
        for (int e = 0; e < 4; ++e) { w[e] = (short)f2bf(f0[e]); w[e + 4] = (short)f2bf(f1[e]); }
        *(s16x8*)(&x_lds[row * 128 + ((c ^ (row & 15)) << 3)]) = w;
    }

    // B-frags (X-part of weights, k in [256,384)) in registers: [g][tt][kt]
    const float* Wp[3] = {Wz, Wr, Wc};
    const float* bp[3] = {bz, br, bc};
    s16x8 Bf[3][4][4];
    float bias[3][4];
#pragma unroll
    for (int g = 0; g < 3; ++g) {
#pragma unroll
        for (int tt = 0; tt < 4; ++tt) {
            int j = v * 64 + tt * 16 + n;
            bias[g][tt] = bp[g][j];
#pragma unroll
            for (int kt = 0; kt < 4; ++kt) {
                const float* src = Wp[g] + j * WROW + 256 + kt * 32 + quad * 8;
                f32x4 f0 = *(const f32x4*)(src);
                f32x4 f1 = *(const f32x4*)(src + 4);
                s16x8 w;
#pragma unroll
                for (int e = 0; e < 4; ++e) { w[e] = (short)f2bf(f0[e]); w[e + 4] = (short)f2bf(f1[e]); }
                Bf[g][tt][kt] = w;
            }
        }
    }
    __syncthreads();

    const int rowA = l & 15;
#pragma unroll 1
    for (int mt = 0; mt < 16; ++mt) {
        f32x4 acc[3][4];
        f32x4 z4 = {0.f, 0.f, 0.f, 0.f};
#pragma unroll
        for (int g = 0; g < 3; ++g)
#pragma unroll
            for (int tt = 0; tt < 4; ++tt) acc[g][tt] = z4;

#pragma unroll
        for (int kt = 0; kt < 4; ++kt) {
            int row = mt * 16 + rowA;
            s16x8 a = *(const s16x8*)(&x_lds[row * 128 + (((kt * 4 + quad) ^ rowA) << 3)]);
#pragma unroll
            for (int g = 0; g < 3; ++g)
#pragma unroll
                for (int tt = 0; tt < 4; ++tt)
                    acc[g][tt] = __builtin_amdgcn_mfma_f32_16x16x32_bf16(a, Bf[g][tt][kt], acc[g][tt], 0, 0, 0);
        }

#pragma unroll
        for (int g = 0; g < 3; ++g)
#pragma unroll
            for (int tt = 0; tt < 4; ++tt) {
                unsigned r0 = f2bf(acc[g][tt][0] + bias[g][tt]);
                unsigned r1 = f2bf(acc[g][tt][1] + bias[g][tt]);
                unsigned r2 = f2bf(acc[g][tt][2] + bias[g][tt]);
                unsigned r3 = f2bf(acc[g][tt][3] + bias[g][tt]);
                uint2 d; d.x = r0 | (r1 << 16); d.y = r2 | (r3 << 16);
                int chunk = (((t * 16 + mt) * 4 + v) * 3 + g) * 4 + tt;
                *(uint2*)((char*)Gx + (size_t)chunk * 512 + l * 8) = d;
            }
    }
}

// ---------------------------------------------------------------------------
// Phase 2: persistent recurrence. 16 WGs x 512 thr (8 waves, 2 waves/SIMD).
// Each wave handles j = w*32 .. w*32+31 (tt in [0,2)).
// Wz/Wr frags resident in 128 VGPRs; Wc frags in LDS (128 KB, conflict-free b128).
// LDS total: 131072 + 2*8448 = 147968 B.
// ---------------------------------------------------------------------------
__global__ __launch_bounds__(512, 2) void gru_seq(
    const float* __restrict__ Wz, const float* __restrict__ Wr, const float* __restrict__ Wc,
    const unsigned short* __restrict__ Gx,
    float* __restrict__ out)
{
    __shared__ unsigned short wc_lds[65536];     // 128 frags x 64 lanes x 16 B = 128 KB
    __shared__ unsigned short h_lds[16][264];    // +8 pad
    __shared__ unsigned short rh_lds[16][264];

    const int tid  = threadIdx.x;
    const int wg   = blockIdx.x;
    const int l    = tid & 63;
    const int w    = tid >> 6;       // wave 0..7
    const int quad = l >> 4;
    const int n    = l & 15;
    const int rowA = n;

    // resident Wz/Wr frags: Wf[g][tt][kt], j = w*32 + tt*16 + n, k = kt*32 + quad*8
    const float* Wp2[2] = {Wz, Wr};
    s16x8 Wf[2][2][8];
#pragma unroll
    for (int g = 0; g < 2; ++g)
#pragma unroll
        for (int tt = 0; tt < 2; ++tt)
#pragma unroll
            for (int kt = 0; kt < 8; ++kt) {
                int j = w * 32 + tt * 16 + n;
                const float* src = Wp2[g] + j * WROW + kt * 32 + quad * 8;
                f32x4 f0 = *(const f32x4*)(src);
                f32x4 f1 = *(const f32x4*)(src + 4);
                s16x8 wv;
#pragma unroll
                for (int e = 0; e < 4; ++e) { wv[e] = (short)f2bf(f0[e]); wv[e + 4] = (short)f2bf(f1[e]); }
                Wf[g][tt][kt] = wv;
            }

    // build Wc frag table in LDS: frag = jb*8 + kt (jb in [0,16)), 1 KB each,
    // lane ln holds B[k = kt*32 + (ln>>4)*8 .. +7][j = jb*16 + (ln&15)]
    for (int idx = tid; idx < 8192; idx += 512) {
        int fr = idx >> 6, ln = idx & 63;
        int jb = fr >> 3, kt = fr & 7;
        int j = jb * 16 + (ln & 15);
        int k = kt * 32 + (ln >> 4) * 8;
        const float* src = Wc + j * WROW + k;
        f32x4 f0 = *(const f32x4*)(src);
        f32x4 f1 = *(const f32x4*)(src + 4);
        s16x8 wv;
#pragma unroll
        for (int e = 0; e < 4; ++e) { wv[e] = (short)f2bf(f0[e]); wv[e + 4] = (short)f2bf(f1[e]); }
        *(s16x8*)(&wc_lds[idx * 8]) = wv;
    }

    // zero h state
    {
        unsigned short* hz = &h_lds[0][0];
        for (int i = tid; i < 16 * 264; i += 512) hz[i] = 0;
    }
    float hreg[2][4];
#pragma unroll
    for (int tt = 0; tt < 2; ++tt)
#pragma unroll
        for (int r = 0; r < 4; ++r) hreg[tt][r] = 0.0f;
    __syncthreads();

    // Gx addressing: chunk = ((t*16+wg)*4 + (w>>1))*12 + g*4 + (w&1)*2 + tt
    const char* gxbase = (const char*)Gx
        + (size_t)(((wg * 4 + (w >> 1)) * 12 + (w & 1) * 2) * 512) + l * 8;
    float* outp = out + (size_t)(wg * 16 + quad * 4) * 256 + w * 32 + n;
    const f32x4 z4 = {0.f, 0.f, 0.f, 0.f};

#pragma unroll 1
    for (int t = 0; t < SEQ; ++t) {
        const char* gb = gxbase + (size_t)t * 393216;

        // issue all 6 Gx loads now; first use is ~32 MFMAs away
        uint2 ga[6];
#pragma unroll
        for (int i = 0; i < 6; ++i)
            ga[i] = *(const uint2*)(gb + (i >> 1) * 2048 + (i & 1) * 512);

        // z/r MFMA
        f32x4 accZ[2], accR[2];
#pragma unroll
        for (int tt = 0; tt < 2; ++tt) { accZ[tt] = z4; accR[tt] = z4; }
#pragma unroll
        for (int kt = 0; kt < 8; ++kt) {
            s16x8 a = *(const s16x8*)(&h_lds[rowA][kt * 32 + quad * 8]);
#pragma unroll
            for (int tt = 0; tt < 2; ++tt) {
                accZ[tt] = __builtin_amdgcn_mfma_f32_16x16x32_bf16(a, Wf[0][tt][kt], accZ[tt], 0, 0, 0);
                accR[tt] = __builtin_amdgcn_mfma_f32_16x16x32_bf16(a, Wf[1][tt][kt], accR[tt], 0, 0, 0);
            }
        }

        // epilogue 1: z, r, write r*h
        float zs[2][4];
#pragma unroll
        for (int tt = 0; tt < 2; ++tt) {
            uint2 gz = ga[tt], gr = ga[2 + tt];
            float gzf[4] = { bf2f((unsigned short)(gz.x & 0xffffu)), bf2f((unsigned short)(gz.x >> 16)),
                             bf2f((unsigned short)(gz.y & 0xffffu)), bf2f((unsigned short)(gz.y >> 16)) };
            float grf[4] = { bf2f((unsigned short)(gr.x & 0xffffu)), bf2f((unsigned short)(gr.x >> 16)),
                             bf2f((unsigned short)(gr.y & 0xffffu)), bf2f((unsigned short)(gr.y >> 16)) };
#pragma unroll
            for (int r = 0; r < 4; ++r) {
                float zv = sigm(accZ[tt][r] + gzf[r]);
                float rv = sigm(accR[tt][r] + grf[r]);
                zs[tt][r] = zv;
                float rh = rv * hreg[tt][r];
                rh_lds[quad * 4 + r][w * 32 + tt * 16 + n] = (unsigned short)f2bf(rh);
            }
        }
        lds_barrier();   // r*h published; h_lds reads complete

        // candidate MFMA (Wc frags from LDS)
        f32x4 accC[2];
#pragma unroll
        for (int tt = 0; tt < 2; ++tt) accC[tt] = z4;
#pragma unroll
        for (int kt = 0; kt < 8; ++kt) {
            s16x8 a = *(const s16x8*)(&rh_lds[rowA][kt * 32 + quad * 8]);
#pragma unroll
            for (int tt = 0; tt < 2; ++tt) {
                s16x8 b = *(const s16x8*)(&wc_lds[(((w * 2 + tt) * 8 + kt) * 64 + l) * 8]);
                accC[tt] = __builtin_amdgcn_mfma_f32_16x16x32_bf16(a, b, accC[tt], 0, 0, 0);
            }
        }

        // epilogue 2: candidate, h update, stores (stores float across the barrier)
#pragma unroll
        for (int tt = 0; tt < 2; ++tt) {
            uint2 gc = ga[4 + tt];
            float gcf[4] = { bf2f((unsigned short)(gc.x & 0xffffu)), bf2f((unsigned short)(gc.x >> 16)),
                             bf2f((unsigned short)(gc.y & 0xffffu)), bf2f((unsigned short)(gc.y >> 16)) };
#pragma unroll
            for (int r = 0; r < 4; ++r) {
                float cv = tanh_(accC[tt][r] + gcf[r]);
                float h  = hreg[tt][r];
                float hn = fmaf(zs[tt][r], cv - h, h);
                hreg[tt][r] = hn;
                h_lds[quad * 4 + r][w * 32 + tt * 16 + n] = (unsigned short)f2bf(hn);
                outp[(size_t)t * 65536 + r * 256 + tt * 16] = hn;
            }
        }
        lds_barrier();   // h published for next step
    }
}

// ---------------------------------------------------------------------------
// Fallback (only if ws_size < 201 MB): naive fp32, correct but slow.
// ---------------------------------------------------------------------------
__global__ __launch_bounds__(1024, 1) void gru_fallback(
    const float* __restrict__ X,
    const float* __restrict__ Wz, const float* __restrict__ bz,
    const float* __restrict__ Wr, const float* __restrict__ br,
    const float* __restrict__ Wc, const float* __restrict__ bc,
    float* __restrict__ out)
{
    __shared__ float h_s[16][257];
    __shared__ float rh_s[16][257];
    __shared__ float x_s[16][128];
    const int tid = threadIdx.x;
    const int wg = blockIdx.x, b0 = wg * 16;
    const int m = tid >> 6, jq = tid & 63;
    for (int i = tid; i < 16 * 257; i += 1024) (&h_s[0][0])[i] = 0.0f;
    __syncthreads();
    for (int t = 0; t < SEQ; ++t) {
        for (int i = tid; i < 2048; i += 1024) {
            int row = i >> 7, k = i & 127;
            x_s[row][k] = X[(size_t)((b0 + row) * SEQ + t) * NI + k];
        }
        __syncthreads();
        float zv[4];
        for (int jj = 0; jj < 4; ++jj) {
            int j = jj * 64 + jq;
            float az = bz[j], ar = br[j];
            for (int k = 0; k < 256; ++k) { float h = h_s[m][k]; az += h * Wz[j * WROW + k]; ar += h * Wr[j * WROW + k]; }
            for (int k = 0; k < 128; ++k) { float x = x_s[m][k]; az += x * Wz[j * WROW + 256 + k]; ar += x * Wr[j * WROW + 256 + k]; }
            float z = sigm(az), r = sigm(ar);
            zv[jj] = z;
            rh_s[m][j] = r * h_s[m][j];
        }
        __syncthreads();
        float hn[4];
        for (int jj = 0; jj < 4; ++jj) {
            int j = jj * 64 + jq;
            float ac = bc[j];
            for (int k = 0; k < 256; ++k) ac += rh_s[m][k] * Wc[j * WROW + k];
            for (int k = 0; k < 128; ++k) ac += x_s[m][k] * Wc[j * WROW + 256 + k];
            float c = tanh_(ac);
            float h = h_s[m][j];
            hn[jj] = fmaf(zv[jj], c - h, h);
        }
        __syncthreads();
        for (int jj = 0; jj < 4; ++jj) {
            int j = jj * 64 + jq;
            h_s[m][j] = hn[jj];
            out[(size_t)(t * 256 + b0 + m) * 256 + j] = hn[jj];
        }
        __syncthreads();
    }
}

extern "C" void kernel_launch(void* const* d_in, const int* in_sizes, int n_in,
                              void* d_out, int out_size, void* d_ws, size_t ws_size,
                              hipStream_t stream) {
    const float* X  = (const float*)d_in[0];
    const float* Wz = (const float*)d_in[1];
    const float* bz = (const float*)d_in[2];
    const float* Wr = (const float*)d_in[3];
    const float* br = (const float*)d_in[4];
    const float* Wc = (const float*)d_in[5];
    const float* bc = (const float*)d_in[6];
    float* out = (float*)d_out;

    if (ws_size >= GX_BYTES) {
        unsigned short* Gx = (unsigned short*)d_ws;
        gru_xpre<<<512, 256, 0, stream>>>(X, Wz, bz, Wr, br, Wc, bc, Gx);
        gru_seq<<<16, 512, 0, stream>>>(Wz, Wr, Wc, Gx, out);
    } else {
        gru_fallback<<<16, 1024, 0, stream>>>(X, Wz, bz, Wr, br, Wc, bc, out);
    }
}